// Round 3
// baseline (870.608 us; speedup 1.0000x reference)
//
#include <hip/hip_runtime.h>

#define NX 512
#define NY 512
#define NZ 256
#define NBUCKET (512 * 512)   // morton(ix0, iy0), 9+9 bits

typedef float v4f __attribute__((ext_vector_type(4)));

struct Payload { int b00; float wx, wy, wz; int idx; };  // 20 B, dword-aligned

__device__ __forceinline__ unsigned spread9(unsigned v) {
    v = (v | (v << 8)) & 0x00FF00FFu;
    v = (v | (v << 4)) & 0x0F0F0F0Fu;
    v = (v | (v << 2)) & 0x33333333u;
    v = (v | (v << 1)) & 0x55555555u;
    return v;
}

struct PtPrep {
    int b00;
    int ix0, iy0;
    float wx, wy, wz;
    bool valid;
};

__device__ __forceinline__ PtPrep prep(float px, float py, float pz,
                                       float lx, float ly, float lz,
                                       float rx, float ry, float rz) {
    PtPrep r;
    float fx = (px - lx) * rx;
    float fy = (py - ly) * ry;
    float fz = (pz - lz) * rz;
    r.valid = (fx >= 0.0f) && (fx <= (float)(NX - 1)) &&
              (fy >= 0.0f) && (fy <= (float)(NY - 1)) &&
              (fz >= 0.0f) && (fz <= (float)(NZ - 1));
    int ix0 = min(max((int)floorf(fx), 0), NX - 2);
    int iy0 = min(max((int)floorf(fy), 0), NY - 2);
    int iz0 = min(max((int)floorf(fz), 0), NZ - 2);
    r.wx = fx - (float)ix0;
    r.wy = fy - (float)iy0;
    r.wz = fz - (float)iz0;
    r.ix0 = ix0; r.iy0 = iy0;
    r.b00 = (ix0 * NY + iy0) * NZ + iz0;
    return r;
}

__device__ __forceinline__ void finish(const v4f& v00, const v4f& v01,
                                       const v4f& v10, const v4f& v11,
                                       float wx, float wy, float wz,
                                       float& sigma, float& alpha) {
    float uz = 1.0f - wz, uy = 1.0f - wy, ux = 1.0f - wx;
    float s00 = v00.x * uz + v00.z * wz;
    float a00 = v00.y * uz + v00.w * wz;
    float s01 = v01.x * uz + v01.z * wz;
    float a01 = v01.y * uz + v01.w * wz;
    float s10 = v10.x * uz + v10.z * wz;
    float a10 = v10.y * uz + v10.w * wz;
    float s11 = v11.x * uz + v11.z * wz;
    float a11 = v11.y * uz + v11.w * wz;
    sigma = ux * (uy * s00 + wy * s01) + wx * (uy * s10 + wy * s11);
    alpha = ux * (uy * a00 + wy * a01) + wx * (uy * a10 + wy * a11);
}

// ---- pass 0: zero histogram ----
__global__ __launch_bounds__(256) void zero_kernel(unsigned* __restrict__ hist) {
    int i = blockIdx.x * blockDim.x + threadIdx.x;
    if (i < NBUCKET) hist[i] = 0u;
}

// ---- pass 1: histogram ----
__global__ __launch_bounds__(256) void hist_kernel(
    const float* __restrict__ x,
    const float* __restrict__ lower,
    const float* __restrict__ resolution,
    unsigned* __restrict__ hist, int n)
{
    int i = blockIdx.x * blockDim.x + threadIdx.x;
    if (i >= n) return;
    PtPrep p = prep(x[3*i], x[3*i+1], x[3*i+2],
                    lower[0], lower[1], lower[2],
                    resolution[0], resolution[1], resolution[2]);
    if (!p.valid) return;
    unsigned key = spread9((unsigned)p.ix0) | (spread9((unsigned)p.iy0) << 1);
    atomicAdd(&hist[key], 1u);
}

// ---- pass 2: exclusive scan (3 kernels) ----
__global__ __launch_bounds__(1024) void scan_block_kernel(
    unsigned* __restrict__ hist, unsigned* __restrict__ bsum)
{
    __shared__ unsigned s[1024];
    int t = threadIdx.x;
    int g = blockIdx.x * 1024 + t;
    unsigned v = hist[g];
    s[t] = v;
    __syncthreads();
    // Hillis-Steele inclusive scan
    for (int off = 1; off < 1024; off <<= 1) {
        unsigned u = (t >= off) ? s[t - off] : 0u;
        __syncthreads();
        s[t] += u;
        __syncthreads();
    }
    hist[g] = s[t] - v;  // exclusive within block
    if (t == 1023) bsum[blockIdx.x] = s[t];
}

__global__ __launch_bounds__(256) void scan_bsum_kernel(unsigned* __restrict__ bsum) {
    __shared__ unsigned s[256];
    int t = threadIdx.x;
    unsigned v = bsum[t];
    s[t] = v;
    __syncthreads();
    for (int off = 1; off < 256; off <<= 1) {
        unsigned u = (t >= off) ? s[t - off] : 0u;
        __syncthreads();
        s[t] += u;
        __syncthreads();
    }
    bsum[t] = s[t] - v;  // exclusive
}

__global__ __launch_bounds__(256) void scan_add_kernel(
    unsigned* __restrict__ hist, const unsigned* __restrict__ bsum)
{
    int g = blockIdx.x * blockDim.x + threadIdx.x;
    if (g < NBUCKET) hist[g] += bsum[g >> 10];
}

// ---- pass 3: scatter payloads into sorted order ----
__global__ __launch_bounds__(256) void scatter_kernel(
    const float* __restrict__ x,
    const float* __restrict__ lower,
    const float* __restrict__ resolution,
    unsigned* __restrict__ cursor,
    Payload* __restrict__ pay,
    float* __restrict__ out, int n)
{
    int i = blockIdx.x * blockDim.x + threadIdx.x;
    if (i >= n) return;
    PtPrep p = prep(x[3*i], x[3*i+1], x[3*i+2],
                    lower[0], lower[1], lower[2],
                    resolution[0], resolution[1], resolution[2]);
    if (!p.valid) {
        out[i] = 0.0f;
        out[n + i] = 0.0f;
        return;
    }
    unsigned key = spread9((unsigned)p.ix0) | (spread9((unsigned)p.iy0) << 1);
    unsigned pos = atomicAdd(&cursor[key], 1u);
    Payload pl;
    pl.b00 = p.b00; pl.wx = p.wx; pl.wy = p.wy; pl.wz = p.wz; pl.idx = i;
    pay[pos] = pl;
}

// ---- pass 4: gather in sorted (grid-local) order ----
__global__ __launch_bounds__(256) void gather_kernel(
    const Payload* __restrict__ pay,
    const float* __restrict__ grid,
    const unsigned* __restrict__ cursor,
    float* __restrict__ out, int n)
{
    unsigned total = cursor[NBUCKET - 1];  // inclusive prefix after scatter = valid count
    unsigned j = blockIdx.x * blockDim.x + threadIdx.x;
    if (j >= total) return;
    Payload p = pay[j];
    const float2* g = (const float2*)grid;
    v4f v00, v01, v10, v11;
    __builtin_memcpy(&v00, g + p.b00, 16);
    __builtin_memcpy(&v01, g + p.b00 + NZ, 16);
    __builtin_memcpy(&v10, g + p.b00 + NY * NZ, 16);
    __builtin_memcpy(&v11, g + p.b00 + NY * NZ + NZ, 16);
    float sigma, alpha;
    finish(v00, v01, v10, v11, p.wx, p.wy, p.wz, sigma, alpha);
    out[p.idx] = sigma;
    out[n + p.idx] = alpha;
}

// ---- fallback: direct kernel (used if ws too small) ----
__global__ __launch_bounds__(256) void direct_kernel(
    const float* __restrict__ x,
    const float* __restrict__ grid,
    const float* __restrict__ lower,
    const float* __restrict__ resolution,
    float* __restrict__ out, int n)
{
    int i = blockIdx.x * blockDim.x + threadIdx.x;
    if (i >= n) return;
    PtPrep p = prep(x[3*i], x[3*i+1], x[3*i+2],
                    lower[0], lower[1], lower[2],
                    resolution[0], resolution[1], resolution[2]);
    float sigma = 0.0f, alpha = 0.0f;
    if (p.valid) {
        const float2* g = (const float2*)grid;
        v4f v00, v01, v10, v11;
        __builtin_memcpy(&v00, g + p.b00, 16);
        __builtin_memcpy(&v01, g + p.b00 + NZ, 16);
        __builtin_memcpy(&v10, g + p.b00 + NY * NZ, 16);
        __builtin_memcpy(&v11, g + p.b00 + NY * NZ + NZ, 16);
        finish(v00, v01, v10, v11, p.wx, p.wy, p.wz, sigma, alpha);
    }
    out[i] = sigma;
    out[n + i] = alpha;
}

extern "C" void kernel_launch(void* const* d_in, const int* in_sizes, int n_in,
                              void* d_out, int out_size, void* d_ws, size_t ws_size,
                              hipStream_t stream) {
    const float* x          = (const float*)d_in[0];
    const float* grid       = (const float*)d_in[1];
    const float* lower      = (const float*)d_in[2];
    const float* resolution = (const float*)d_in[3];
    float* out              = (float*)d_out;

    int n = in_sizes[0] / 3;  // x is [N,3]
    int block = 256;
    int pblocks = (n + block - 1) / block;

    size_t histBytes = (size_t)NBUCKET * 4;          // 1 MiB
    size_t bsumBytes = 256 * 4;
    size_t payBytes  = (size_t)n * sizeof(Payload);  // ~40 MiB
    size_t need = histBytes + bsumBytes + payBytes + 64;

    if (ws_size < need) {
        direct_kernel<<<pblocks, block, 0, stream>>>(x, grid, lower, resolution, out, n);
        return;
    }

    unsigned* hist = (unsigned*)d_ws;
    unsigned* bsum = (unsigned*)((char*)d_ws + histBytes);
    Payload*  pay  = (Payload*)((char*)d_ws + histBytes + 64);  // 64B pad past bsum

    zero_kernel<<<(NBUCKET + 255) / 256, 256, 0, stream>>>(hist);
    hist_kernel<<<pblocks, block, 0, stream>>>(x, lower, resolution, hist, n);
    scan_block_kernel<<<NBUCKET / 1024, 1024, 0, stream>>>(hist, bsum);
    scan_bsum_kernel<<<1, 256, 0, stream>>>(bsum);
    scan_add_kernel<<<NBUCKET / 256, 256, 0, stream>>>(hist, bsum);
    scatter_kernel<<<pblocks, block, 0, stream>>>(x, lower, resolution, hist, pay, out, n);
    gather_kernel<<<pblocks, block, 0, stream>>>(pay, grid, hist, out, n);
}

// Round 6
// 718.169 us; speedup vs baseline: 1.2123x; 1.2123x over previous
//
#include <hip/hip_runtime.h>

#define NX 512
#define NY 512
#define NZ 256

typedef float v4f __attribute__((ext_vector_type(4)));

// One point per thread. Per point: 4 independent 16B gathers (z-pair fused),
// branchless validity (invalid lanes alias index 0 -> one cached line),
// coalesced x reads and out writes.
__global__ __launch_bounds__(256) void trilerp_kernel(
    const float* __restrict__ x,
    const float* __restrict__ grid,
    const float* __restrict__ lower,
    const float* __restrict__ resolution,
    float* __restrict__ out,
    int n)
{
    int i = blockIdx.x * blockDim.x + threadIdx.x;
    if (i >= n) return;

    float px = x[3 * i + 0];
    float py = x[3 * i + 1];
    float pz = x[3 * i + 2];

    float fx = (px - lower[0]) * resolution[0];
    float fy = (py - lower[1]) * resolution[1];
    float fz = (pz - lower[2]) * resolution[2];

    bool valid = (fx >= 0.0f) && (fx <= (float)(NX - 1)) &&
                 (fy >= 0.0f) && (fy <= (float)(NY - 1)) &&
                 (fz >= 0.0f) && (fz <= (float)(NZ - 1));

    // Clamp base so corner+1 is in-bounds and the z-pair is contiguous.
    // wx = fx - ix0 reproduces the reference's clamped interpolation exactly
    // (fx == NX-1 -> ix0 = NX-2, wx = 1.0 -> selects plane NX-1).
    int ix0 = min(max((int)floorf(fx), 0), NX - 2);
    int iy0 = min(max((int)floorf(fy), 0), NY - 2);
    int iz0 = min(max((int)floorf(fz), 0), NZ - 2);
    float wx = fx - (float)ix0;
    float wy = fy - (float)iy0;
    float wz = fz - (float)iz0;

    int row0 = (ix0 * NY + iy0) * NZ + iz0;
    int b00 = valid ? row0 : 0;
    int b01 = valid ? row0 + NZ : 0;
    int b10 = valid ? row0 + NY * NZ : 0;
    int b11 = valid ? row0 + NY * NZ + NZ : 0;

    const float2* __restrict__ g = (const float2*)grid;

    // 4 independent 16B loads: {sigma(z0), alpha(z0), sigma(z1), alpha(z1)}
    v4f v00, v01, v10, v11;
    __builtin_memcpy(&v00, g + b00, 16);
    __builtin_memcpy(&v01, g + b01, 16);
    __builtin_memcpy(&v10, g + b10, 16);
    __builtin_memcpy(&v11, g + b11, 16);

    float uz = 1.0f - wz, uy = 1.0f - wy, ux = 1.0f - wx;
    float s00 = v00.x * uz + v00.z * wz;
    float a00 = v00.y * uz + v00.w * wz;
    float s01 = v01.x * uz + v01.z * wz;
    float a01 = v01.y * uz + v01.w * wz;
    float s10 = v10.x * uz + v10.z * wz;
    float a10 = v10.y * uz + v10.w * wz;
    float s11 = v11.x * uz + v11.z * wz;
    float a11 = v11.y * uz + v11.w * wz;

    float sigma = ux * (uy * s00 + wy * s01) + wx * (uy * s10 + wy * s11);
    float alpha = ux * (uy * a00 + wy * a01) + wx * (uy * a10 + wy * a11);

    if (!valid) { sigma = 0.0f; alpha = 0.0f; }

    out[i] = sigma;
    out[n + i] = alpha;
}

extern "C" void kernel_launch(void* const* d_in, const int* in_sizes, int n_in,
                              void* d_out, int out_size, void* d_ws, size_t ws_size,
                              hipStream_t stream) {
    const float* x          = (const float*)d_in[0];
    const float* grid       = (const float*)d_in[1];
    const float* lower      = (const float*)d_in[2];
    const float* resolution = (const float*)d_in[3];
    float* out              = (float*)d_out;

    int n = in_sizes[0] / 3;  // x is [N,3]
    int block = 256;
    int blocks = (n + block - 1) / block;
    trilerp_kernel<<<blocks, block, 0, stream>>>(x, grid, lower, resolution, out, n);
}